// Round 1
// baseline (33250.247 us; speedup 1.0000x reference)
//
#include <hip/hip_runtime.h>
#include <hip/hip_bf16.h>
#include <math.h>

// ---------------- model constants ----------------
#define D_MODEL   1024
#define D_INNER   2048
#define D_STATE   16
#define D_CONV    4
#define DT_RANK   64
#define N_LAYERS  24
#define SEQ       577      // 1 cls + 24*24 patches
#define BATCH     2
#define ROWS      (BATCH*SEQ)   // 1154

// ---------------- patch embed + positional ----------------
__global__ __launch_bounds__(256) void embed_kernel(
    const float* __restrict__ x,     // (2,3,192,192)
    const float* __restrict__ pe_w,  // (1024,3,8,8)
    const float* __restrict__ pe_b,  // (1024)
    const float* __restrict__ cls,   // (1024)
    float* __restrict__ tok)         // (2,577,1024)
{
    const int t = blockIdx.x;   // 0..576
    const int b = blockIdx.y;
    float* out = tok + ((size_t)b*SEQ + t)*D_MODEL;
    if (t == 0) {
        for (int d = threadIdx.x; d < D_MODEL; d += 256) out[d] = cls[d];
        return;
    }
    const int hp = (t-1)/24, wp = (t-1)%24;
    __shared__ float patch[192];
    if (threadIdx.x < 192) {
        int c = threadIdx.x >> 6;
        int p = (threadIdx.x >> 3) & 7;
        int q = threadIdx.x & 7;
        patch[threadIdx.x] = x[(((size_t)b*3 + c)*192 + hp*8 + p)*192 + wp*8 + q];
    }
    __syncthreads();
    const float LOG1E4_256 = 9.210340371976184f / 256.0f;  // ln(10000)/256
    #pragma unroll
    for (int jj = 0; jj < 4; jj++) {
        int d = threadIdx.x + jj*256;
        const float* w = pe_w + (size_t)d*192;
        float acc = 0.f;
        #pragma unroll 4
        for (int k = 0; k < 192; k++) acc += patch[k]*w[k];
        int dm = d & 255;
        float invf = __expf(-(float)dm * LOG1E4_256);
        // use precise expf to match fp32 reference closely
        invf = expf(-(float)dm * LOG1E4_256);
        float arg = ((d < 512) ? (float)hp : (float)wp) * invf;
        float pos = (d & 256) ? cosf(arg) : sinf(arg);
        out[d] = acc + pe_b[d] + pos;
    }
}

// ---------------- layernorm (rows of 1024) ----------------
__global__ __launch_bounds__(256) void ln_kernel(
    const float* __restrict__ x, const float* __restrict__ g,
    const float* __restrict__ bb, float* __restrict__ o, int rows)
{
    const int r = blockIdx.x;
    if (r >= rows) return;
    const float4 v = reinterpret_cast<const float4*>(x + (size_t)r*D_MODEL)[threadIdx.x];
    float s = v.x + v.y + v.z + v.w;
    __shared__ float red[4], red2[4];
    #pragma unroll
    for (int m = 1; m < 64; m <<= 1) s += __shfl_xor(s, m);
    if ((threadIdx.x & 63) == 0) red[threadIdx.x >> 6] = s;
    __syncthreads();
    float mean = (red[0]+red[1]+red[2]+red[3]) * (1.f/1024.f);
    float d0 = v.x-mean, d1 = v.y-mean, d2 = v.z-mean, d3 = v.w-mean;
    float q = d0*d0 + d1*d1 + d2*d2 + d3*d3;
    #pragma unroll
    for (int m = 1; m < 64; m <<= 1) q += __shfl_xor(q, m);
    if ((threadIdx.x & 63) == 0) red2[threadIdx.x >> 6] = q;
    __syncthreads();
    float var = (red2[0]+red2[1]+red2[2]+red2[3]) * (1.f/1024.f);
    float rstd = rsqrtf(var + 1e-5f);
    const float4 gg = reinterpret_cast<const float4*>(g)[threadIdx.x];
    const float4 bv = reinterpret_cast<const float4*>(bb)[threadIdx.x];
    float4 ov;
    ov.x = d0*rstd*gg.x + bv.x;
    ov.y = d1*rstd*gg.y + bv.y;
    ov.z = d2*rstd*gg.z + bv.z;
    ov.w = d3*rstd*gg.w + bv.w;
    reinterpret_cast<float4*>(o + (size_t)r*D_MODEL)[threadIdx.x] = ov;
}

// ---------------- generic fp32 NT GEMM: C = A(MxK) * B(NxK)^T ----------------
// act: 0 = none, 1 = softplus(v+bias), 2 = gelu(v+bias), bias may be null.
// resid != null -> v += resid[m*ldc+n]
#define BM 64
#define BN 64
#define BK 16
__global__ __launch_bounds__(256) void gemm_nt_kernel(
    const float* __restrict__ A, int lda,
    const float* __restrict__ B, int ldb,
    float* __restrict__ C, int ldc,
    int M, int N, int K,
    const float* __restrict__ bias,
    const float* __restrict__ resid,
    int act)
{
    __shared__ float As[BK][BM+4];
    __shared__ float Bs[BK][BN+4];
    const int tid = threadIdx.x;
    const int bm = blockIdx.y * BM;
    const int bn = blockIdx.x * BN;
    const int tx = tid & 15;        // n tile idx
    const int ty = tid >> 4;        // m tile idx
    const int lr = tid >> 2;        // load row 0..63
    const int lc = (tid & 3) << 2;  // load col 0,4,8,12

    float acc[4][4];
    #pragma unroll
    for (int i = 0; i < 4; i++)
        #pragma unroll
        for (int j = 0; j < 4; j++) acc[i][j] = 0.f;

    for (int k0 = 0; k0 < K; k0 += BK) {
        float4 av = make_float4(0.f,0.f,0.f,0.f);
        if (bm + lr < M)
            av = *reinterpret_cast<const float4*>(A + (size_t)(bm+lr)*lda + k0 + lc);
        As[lc+0][lr] = av.x; As[lc+1][lr] = av.y; As[lc+2][lr] = av.z; As[lc+3][lr] = av.w;
        float4 bv = make_float4(0.f,0.f,0.f,0.f);
        if (bn + lr < N)
            bv = *reinterpret_cast<const float4*>(B + (size_t)(bn+lr)*ldb + k0 + lc);
        Bs[lc+0][lr] = bv.x; Bs[lc+1][lr] = bv.y; Bs[lc+2][lr] = bv.z; Bs[lc+3][lr] = bv.w;
        __syncthreads();
        #pragma unroll
        for (int kk = 0; kk < BK; kk++) {
            const float4 a = *reinterpret_cast<const float4*>(&As[kk][ty*4]);
            const float4 b = *reinterpret_cast<const float4*>(&Bs[kk][tx*4]);
            acc[0][0] += a.x*b.x; acc[0][1] += a.x*b.y; acc[0][2] += a.x*b.z; acc[0][3] += a.x*b.w;
            acc[1][0] += a.y*b.x; acc[1][1] += a.y*b.y; acc[1][2] += a.y*b.z; acc[1][3] += a.y*b.w;
            acc[2][0] += a.z*b.x; acc[2][1] += a.z*b.y; acc[2][2] += a.z*b.z; acc[2][3] += a.z*b.w;
            acc[3][0] += a.w*b.x; acc[3][1] += a.w*b.y; acc[3][2] += a.w*b.z; acc[3][3] += a.w*b.w;
        }
        __syncthreads();
    }

    #pragma unroll
    for (int i = 0; i < 4; i++) {
        int m = bm + ty*4 + i;
        if (m >= M) continue;
        #pragma unroll
        for (int j = 0; j < 4; j++) {
            int n = bn + tx*4 + j;
            if (n >= N) continue;
            float v = acc[i][j];
            if (bias) v += bias[n];
            if (act == 1) {               // softplus
                v = fmaxf(v, 0.f) + log1pf(expf(-fabsf(v)));
            } else if (act == 2) {        // exact gelu
                v = 0.5f*v*(1.f + erff(v*0.70710678118654752440f));
            }
            if (resid) v += resid[(size_t)m*ldc + n];
            C[(size_t)m*ldc + n] = v;
        }
    }
}

// ---------------- depthwise causal conv (k=4) + silu ----------------
__global__ __launch_bounds__(256) void conv_silu_kernel(
    const float* __restrict__ xz,   // (B,SEQ,4096), xh = cols [0,2048)
    const float* __restrict__ dcw,  // (2048,4)
    const float* __restrict__ dcb,  // (2048)
    float* __restrict__ xc)         // (B,SEQ,2048)
{
    int g = blockIdx.x*256 + threadIdx.x;
    const int total = BATCH*SEQ*D_INNER;
    if (g >= total) return;
    int d  = g & (D_INNER-1);
    int bt = g >> 11;
    int t  = bt % SEQ;
    int b  = bt / SEQ;
    const float4 w = *reinterpret_cast<const float4*>(dcw + (size_t)d*4);
    float v = dcb[d];
    const float ws[4] = {w.x, w.y, w.z, w.w};
    #pragma unroll
    for (int k = 0; k < 4; k++) {
        int tt = t + k - 3;
        if (tt >= 0) v += xz[((size_t)b*SEQ + tt)*(2*D_INNER) + d] * ws[k];
    }
    v = v / (1.f + expf(-v));       // silu
    xc[g] = v;
}

// ---------------- selective scan (thread per (b,d,s)) ----------------
__global__ __launch_bounds__(256) void scan_kernel(
    const float* __restrict__ dt,    // (B,SEQ,2048)
    const float* __restrict__ dbc,   // (B,SEQ,96): [.,64:80]=Bm, [.,80:96]=Cm
    const float* __restrict__ xc,    // (B,SEQ,2048)
    const float* __restrict__ xz,    // (B,SEQ,4096): z = cols [2048,4096)
    const float* __restrict__ A_log, // (2048,16) for this layer
    const float* __restrict__ Dp,    // (2048)
    float* __restrict__ y)           // (B,SEQ,2048)
{
    const int b = blockIdx.y;
    const int dl = threadIdx.x >> 4;
    const int s  = threadIdx.x & 15;
    const int d  = blockIdx.x*16 + dl;
    const float A = -expf(A_log[(size_t)d*D_STATE + s]);
    const float Dpd = Dp[d];
    float h = 0.f;
    const size_t base = (size_t)b*SEQ;
    for (int t = 0; t < SEQ; t++) {
        const size_t rt = base + t;
        const float dtv = dt[rt*D_INNER + d];
        const float xv  = xc[rt*D_INNER + d];
        const float Bv  = dbc[rt*96 + DT_RANK + s];
        const float Cv  = dbc[rt*96 + DT_RANK + D_STATE + s];
        h = expf(dtv*A)*h + (dtv*xv)*Bv;
        float p = h*Cv;
        p += __shfl_xor(p, 1, 16);
        p += __shfl_xor(p, 2, 16);
        p += __shfl_xor(p, 4, 16);
        p += __shfl_xor(p, 8, 16);
        if (s == 0) {
            const float zv = xz[rt*(2*D_INNER) + D_INNER + d];
            y[rt*D_INNER + d] = (p + xv*Dpd) * (zv/(1.f + expf(-zv)));
        }
    }
}

// ---------------- host-side orchestration ----------------
static inline int cdiv(int a, int b) { return (a + b - 1) / b; }

extern "C" void kernel_launch(void* const* d_in, const int* in_sizes, int n_in,
                              void* d_out, int out_size, void* d_ws, size_t ws_size,
                              hipStream_t stream) {
    const float* x     = (const float*)d_in[0];
    const float* pe_w  = (const float*)d_in[1];
    const float* pe_b  = (const float*)d_in[2];
    const float* cls   = (const float*)d_in[3];
    const float* g1    = (const float*)d_in[4];
    const float* b1    = (const float*)d_in[5];
    const float* in_w  = (const float*)d_in[6];
    const float* dcw   = (const float*)d_in[7];
    const float* dcb   = (const float*)d_in[8];
    const float* xpw   = (const float*)d_in[9];
    const float* dtw   = (const float*)d_in[10];
    const float* dtb   = (const float*)d_in[11];
    const float* A_log = (const float*)d_in[12];
    const float* Dp    = (const float*)d_in[13];
    const float* ow    = (const float*)d_in[14];
    const float* g2    = (const float*)d_in[15];
    const float* b2    = (const float*)d_in[16];
    const float* f1w   = (const float*)d_in[17];
    const float* f1b   = (const float*)d_in[18];
    const float* f2w   = (const float*)d_in[19];
    const float* f2b   = (const float*)d_in[20];
    float* out = (float*)d_out;

    float* ws = (float*)d_ws;
    // workspace layout (floats)
    float* tokens = ws;                       // 1181696
    float* hbuf   = tokens + (size_t)ROWS*D_MODEL;          // 1181696
    float* xz     = hbuf   + (size_t)ROWS*D_MODEL;          // 4726784
    float* xc     = xz     + (size_t)ROWS*2*D_INNER;        // 2363392
    float* dbc    = xc     + (size_t)ROWS*D_INNER;          // 110784
    float* dtbuf  = dbc    + (size_t)ROWS*96;               // 2363392
    float* ybuf   = dtbuf  + (size_t)ROWS*D_INNER;          // 2363392
    float* mo     = ybuf   + (size_t)ROWS*D_INNER;          // 1181696
    float* h2     = mo     + (size_t)ROWS*D_MODEL;          // 1181696
    float* f1o    = h2     + (size_t)ROWS*D_MODEL;          // 4726784

    // ---- embed ----
    {
        dim3 grid(SEQ, BATCH);
        hipLaunchKernelGGL(embed_kernel, grid, dim3(256), 0, stream,
                           x, pe_w, pe_b, cls, tokens);
    }

    for (int l = 0; l < N_LAYERS; l++) {
        const float* g1_l  = g1  + (size_t)l*D_MODEL;
        const float* b1_l  = b1  + (size_t)l*D_MODEL;
        const float* inw_l = in_w+ (size_t)l*2*D_INNER*D_MODEL;
        const float* dcw_l = dcw + (size_t)l*D_INNER*D_CONV;
        const float* dcb_l = dcb + (size_t)l*D_INNER;
        const float* xpw_l = xpw + (size_t)l*(DT_RANK+2*D_STATE)*D_INNER;
        const float* dtw_l = dtw + (size_t)l*D_INNER*DT_RANK;
        const float* dtb_l = dtb + (size_t)l*D_INNER;
        const float* Al_l  = A_log + (size_t)l*D_INNER*D_STATE;
        const float* Dp_l  = Dp  + (size_t)l*D_INNER;
        const float* ow_l  = ow  + (size_t)l*D_MODEL*D_INNER;
        const float* g2_l  = g2  + (size_t)l*D_MODEL;
        const float* b2_l  = b2  + (size_t)l*D_MODEL;
        const float* f1w_l = f1w + (size_t)l*4*D_MODEL*D_MODEL;
        const float* f1b_l = f1b + (size_t)l*4*D_MODEL;
        const float* f2w_l = f2w + (size_t)l*D_MODEL*4*D_MODEL;
        const float* f2b_l = f2b + (size_t)l*D_MODEL;

        // 1. LN1
        hipLaunchKernelGGL(ln_kernel, dim3(ROWS), dim3(256), 0, stream,
                           tokens, g1_l, b1_l, hbuf, ROWS);
        // 2. in_proj: xz = hbuf @ in_w^T   (1154 x 4096, K=1024)
        hipLaunchKernelGGL(gemm_nt_kernel, dim3(2*D_INNER/BN, cdiv(ROWS,BM)), dim3(256), 0, stream,
                           hbuf, D_MODEL, inw_l, D_MODEL, xz, 2*D_INNER,
                           ROWS, 2*D_INNER, D_MODEL, nullptr, nullptr, 0);
        // 3. conv + silu -> xc
        hipLaunchKernelGGL(conv_silu_kernel, dim3(cdiv(ROWS*D_INNER,256)), dim3(256), 0, stream,
                           xz, dcw_l, dcb_l, xc);
        // 4. x_proj: dbc = xc @ xpw^T  (1154 x 96, K=2048)
        hipLaunchKernelGGL(gemm_nt_kernel, dim3(cdiv(96,BN), cdiv(ROWS,BM)), dim3(256), 0, stream,
                           xc, D_INNER, xpw_l, D_INNER, dbc, 96,
                           ROWS, 96, D_INNER, nullptr, nullptr, 0);
        // 5. dt = softplus(dbc[:, :64] @ dtw^T + dtb)  (1154 x 2048, K=64)
        hipLaunchKernelGGL(gemm_nt_kernel, dim3(D_INNER/BN, cdiv(ROWS,BM)), dim3(256), 0, stream,
                           dbc, 96, dtw_l, DT_RANK, dtbuf, D_INNER,
                           ROWS, D_INNER, DT_RANK, dtb_l, nullptr, 1);
        // 6. selective scan -> y (fused +xc*Dp and *silu(z))
        hipLaunchKernelGGL(scan_kernel, dim3(D_INNER/16, BATCH), dim3(256), 0, stream,
                           dtbuf, dbc, xc, xz, Al_l, Dp_l, ybuf);
        // 7. out_proj: mo = y @ ow^T  (1154 x 1024, K=2048)
        hipLaunchKernelGGL(gemm_nt_kernel, dim3(D_MODEL/BN, cdiv(ROWS,BM)), dim3(256), 0, stream,
                           ybuf, D_INNER, ow_l, D_INNER, mo, D_MODEL,
                           ROWS, D_MODEL, D_INNER, nullptr, nullptr, 0);
        // 8. LN2
        hipLaunchKernelGGL(ln_kernel, dim3(ROWS), dim3(256), 0, stream,
                           mo, g2_l, b2_l, h2, ROWS);
        // 9. f1: f1o = gelu(h2 @ f1w^T + f1b)  (1154 x 4096, K=1024)
        hipLaunchKernelGGL(gemm_nt_kernel, dim3(4*D_MODEL/BN, cdiv(ROWS,BM)), dim3(256), 0, stream,
                           h2, D_MODEL, f1w_l, D_MODEL, f1o, 4*D_MODEL,
                           ROWS, 4*D_MODEL, D_MODEL, f1b_l, nullptr, 2);
        // 10. f2 + residual: tokens = tokens + (f1o @ f2w^T + f2b)
        float* dst = (l == N_LAYERS-1) ? out : tokens;
        hipLaunchKernelGGL(gemm_nt_kernel, dim3(D_MODEL/BN, cdiv(ROWS,BM)), dim3(256), 0, stream,
                           f1o, 4*D_MODEL, f2w_l, 4*D_MODEL, dst, D_MODEL,
                           ROWS, D_MODEL, 4*D_MODEL, f2b_l, tokens, 0);
    }
}